// Round 5
// baseline (115.087 us; speedup 1.0000x reference)
//
#include <hip/hip_runtime.h>

#define DIM 16
#define SEQ 2048
#define CHUNK 256            // keys per chunk
#define NCHUNK 8             // SEQ / CHUNK

static __device__ __forceinline__ float fexp2(float x) {
#if __has_builtin(__builtin_amdgcn_exp2f)
    return __builtin_amdgcn_exp2f(x);   // raw v_exp_f32; inputs in [-2.9,2.9]
#else
    return exp2f(x);
#endif
}

// ---------------- quantum circuit primitives (all register-resident) --------

template<int P>
__device__ __forceinline__ void rx_bit(float sr[DIM], float si[DIM], float ch, float sh) {
    constexpr int m = 1 << P;
    #pragma unroll
    for (int i = 0; i < DIM; ++i) {
        if ((i & m) == 0) {
            const int j = i | m;
            float r0 = sr[i], i0 = si[i], r1 = sr[j], i1 = si[j];
            sr[i] = fmaf(ch, r0,  sh * i1);
            si[i] = fmaf(ch, i0, -sh * r1);
            sr[j] = fmaf(ch, r1,  sh * i0);
            si[j] = fmaf(ch, i1, -sh * r0);
        }
    }
}

template<int PC, int PT>
__device__ __forceinline__ void cnot_g(float sr[DIM], float si[DIM]) {
    constexpr int cm = 1 << PC, tm = 1 << PT;
    #pragma unroll
    for (int i = 0; i < DIM; ++i) {
        if ((i & cm) && !(i & tm)) {
            const int j = i | tm;
            float t;
            t = sr[i]; sr[i] = sr[j]; sr[j] = t;
            t = si[i]; si[i] = si[j]; si[j] = t;
        }
    }
}

__device__ __forceinline__ void embed(float sr[DIM], float si[DIM], float4 a) {
    #pragma unroll
    for (int i = 0; i < DIM; ++i) { sr[i] = 0.f; si[i] = 0.f; }
    sr[0] = 1.f;
    float ch, sh;
    __sincosf(0.5f * a.x, &sh, &ch); rx_bit<3>(sr, si, ch, sh);   // wire 0 -> bit 3
    __sincosf(0.5f * a.y, &sh, &ch); rx_bit<2>(sr, si, ch, sh);
    __sincosf(0.5f * a.z, &sh, &ch); rx_bit<1>(sr, si, ch, sh);
    __sincosf(0.5f * a.w, &sh, &ch); rx_bit<0>(sr, si, ch, sh);
}

__device__ __forceinline__ void layer(float sr[DIM], float si[DIM], float4 w) {
    float ch, sh;
    __sincosf(0.5f * w.x, &sh, &ch); rx_bit<3>(sr, si, ch, sh);
    __sincosf(0.5f * w.y, &sh, &ch); rx_bit<2>(sr, si, ch, sh);
    __sincosf(0.5f * w.z, &sh, &ch); rx_bit<1>(sr, si, ch, sh);
    __sincosf(0.5f * w.w, &sh, &ch); rx_bit<0>(sr, si, ch, sh);
    cnot_g<3,2>(sr, si);
    cnot_g<2,1>(sr, si);
    cnot_g<1,0>(sr, si);
    cnot_g<0,3>(sr, si);
}

__device__ __forceinline__ float4 measure(const float sr[DIM], const float si[DIM]) {
    float e0 = 0.f, e1 = 0.f, e2 = 0.f, e3 = 0.f;
    #pragma unroll
    for (int i = 0; i < DIM; ++i) {
        float p = fmaf(sr[i], sr[i], si[i] * si[i]);
        e0 += (i & 8) ? -p : p;
        e1 += (i & 4) ? -p : p;
        e2 += (i & 2) ? -p : p;
        e3 += (i & 1) ? -p : p;
    }
    return make_float4(e0, e1, e2, e3);
}

// ---------------- kernel 1: Q,K,V circuits (split over blockIdx.y) ---------

__global__ __launch_bounds__(256) void qkv_kernel(
        const float* __restrict__ x,
        const float* __restrict__ wQp, const float* __restrict__ wKp,
        const float* __restrict__ wVp,
        float4* __restrict__ Q, float4* __restrict__ KV) {
    const int i = blockIdx.x * 256 + threadIdx.x;
    const int which = blockIdx.y;          // 0=Q, 1=K, 2=V
    const float4 xv = ((const float4*)x)[i];
    const float* wp = (which == 0) ? wQp : (which == 1) ? wKp : wVp;
    const float4 w = *(const float4*)wp;

    float sr[DIM], si[DIM];
    embed(sr, si, xv);
    layer(sr, si, w);
    const float4 r = measure(sr, si);

    if (which == 0)      Q[i]          = r;
    else if (which == 1) KV[2 * i]     = r;   // K interleaved with V
    else                 KV[2 * i + 1] = r;
}

// ---------------- kernel 2: attention partials -----------------------------
// One thread per query row; key chunk per blockIdx.y. K/V addresses are
// wave-uniform (blockIdx + uniform loop index on a __restrict const
// pointer) -> compiler's uniformity analysis turns them into s_load
// scalar broadcasts: zero LDS traffic, zero VALU address math, data held
// in SGPRs. VGPR-light (~32) -> 8 waves/SIMD to saturate VALU issue.

__global__ __launch_bounds__(256, 8) void attn_partial(
        const float4* __restrict__ Q, const float4* __restrict__ KV,
        float* __restrict__ pden, float4* __restrict__ pctx, int n) {
    const int rg = blockIdx.x;          // row-group (256 rows)
    const int c  = blockIdx.y;          // key chunk
    const int b  = rg >> 3;             // 8 row-groups per batch

    const int row = rg * 256 + threadIdx.x;
    const float4 q = Q[row];
    // fold 0.5 (1/sqrt(E)) * log2(e): loop uses raw exp2
    const float SC = 0.72134752044f;
    const float qx = q.x * SC, qy = q.y * SC, qz = q.z * SC, qw = q.w * SC;

    const float4* KVc = KV + (size_t)b * (2 * SEQ) + c * (2 * CHUNK);

    float den = 0.f, a0 = 0.f, a1 = 0.f, a2 = 0.f, a3 = 0.f;
    #pragma unroll 4
    for (int k = 0; k < CHUNK; ++k) {
        const float4 kv = KVc[2 * k];       // uniform -> s_load broadcast
        const float4 vv = KVc[2 * k + 1];
        float s = fmaf(qx, kv.x, fmaf(qy, kv.y, fmaf(qz, kv.z, qw * kv.w)));
        float e = fexp2(s);                 // s in [-2.89,2.89]: no max needed
        den += e;
        a0 = fmaf(e, vv.x, a0);
        a1 = fmaf(e, vv.y, a1);
        a2 = fmaf(e, vv.z, a2);
        a3 = fmaf(e, vv.w, a3);
    }

    pden[c * n + row] = den;                          // coalesced
    pctx[c * n + row] = make_float4(a0, a1, a2, a3);  // coalesced
}

// ---------------- kernel 3: combine partials + final circuit ---------------

__global__ __launch_bounds__(256) void combine_kernel(
        const float* __restrict__ pden, const float4* __restrict__ pctx,
        const float* __restrict__ wCp, float4* __restrict__ out, int n) {
    const int row = blockIdx.x * 256 + threadIdx.x;

    float d = 0.f;
    float c0 = 0.f, c1 = 0.f, c2 = 0.f, c3 = 0.f;
    #pragma unroll
    for (int c = 0; c < NCHUNK; ++c) {
        d += pden[c * n + row];
        const float4 p = pctx[c * n + row];
        c0 += p.x; c1 += p.y; c2 += p.z; c3 += p.w;
    }
    const float inv = 1.0f / d;
    const float4 ctx = make_float4(c0 * inv, c1 * inv, c2 * inv, c3 * inv);

    const float4 wC = *(const float4*)wCp;
    float sr[DIM], si[DIM];
    embed(sr, si, ctx);
    layer(sr, si, wC);
    out[row] = measure(sr, si);
}

// ---------------- launch ---------------------------------------------------

extern "C" void kernel_launch(void* const* d_in, const int* in_sizes, int n_in,
                              void* d_out, int out_size, void* d_ws, size_t ws_size,
                              hipStream_t stream) {
    const float* x  = (const float*)d_in[0];
    const float* wQ = (const float*)d_in[1];
    const float* wK = (const float*)d_in[2];
    const float* wV = (const float*)d_in[3];
    const float* wC = (const float*)d_in[4];

    const int n = in_sizes[0] / 4;              // B*S = 65536 rows
    float4* Q    = (float4*)d_ws;               // n float4          = 1 MB
    float4* KV   = Q + n;                       // 2n float4         = 2 MB
    float4* pctx = KV + 2 * n;                  // NCHUNK*n float4   = 8 MB
    float*  pden = (float*)(pctx + NCHUNK * n); // NCHUNK*n float    = 2 MB

    dim3 qgrid(n / 256, 3);
    qkv_kernel<<<qgrid, 256, 0, stream>>>(x, wQ, wK, wV, Q, KV);

    dim3 agrid(n / 256, NCHUNK);                // (256, 8) = 2048 blocks
    attn_partial<<<agrid, 256, 0, stream>>>(Q, KV, pden, pctx, n);

    combine_kernel<<<n / 256, 256, 0, stream>>>(pden, pctx, wC, (float4*)d_out, n);
}

// Round 6
// 101.769 us; speedup vs baseline: 1.1309x; 1.1309x over previous
//
#include <hip/hip_runtime.h>

#define DIM 16
#define SEQ 2048
#define CHUNK 256            // keys per chunk
#define NPAIR (CHUNK / 2)    // key pairs per chunk
#define NCHUNK 8             // SEQ / CHUNK
#define RPT 2                // query rows per thread

typedef float v2f __attribute__((ext_vector_type(2)));
typedef float v4f __attribute__((ext_vector_type(4)));

static __device__ __forceinline__ float fexp2(float x) {
#if __has_builtin(__builtin_amdgcn_exp2f)
    return __builtin_amdgcn_exp2f(x);   // raw v_exp_f32; inputs in [-2.9,2.9]
#else
    return exp2f(x);
#endif
}

// ---------------- quantum circuit primitives (all register-resident) --------

template<int P>
__device__ __forceinline__ void rx_bit(float sr[DIM], float si[DIM], float ch, float sh) {
    constexpr int m = 1 << P;
    #pragma unroll
    for (int i = 0; i < DIM; ++i) {
        if ((i & m) == 0) {
            const int j = i | m;
            float r0 = sr[i], i0 = si[i], r1 = sr[j], i1 = si[j];
            sr[i] = fmaf(ch, r0,  sh * i1);
            si[i] = fmaf(ch, i0, -sh * r1);
            sr[j] = fmaf(ch, r1,  sh * i0);
            si[j] = fmaf(ch, i1, -sh * r0);
        }
    }
}

template<int PC, int PT>
__device__ __forceinline__ void cnot_g(float sr[DIM], float si[DIM]) {
    constexpr int cm = 1 << PC, tm = 1 << PT;
    #pragma unroll
    for (int i = 0; i < DIM; ++i) {
        if ((i & cm) && !(i & tm)) {
            const int j = i | tm;
            float t;
            t = sr[i]; sr[i] = sr[j]; sr[j] = t;
            t = si[i]; si[i] = si[j]; si[j] = t;
        }
    }
}

// Fast embed from |0>: state = tensor product of (cos, -i sin) per qubit.
// amp(idx) = (-i)^popcount(idx) * prod(c/s). 24 muls + 4 sincos instead of
// 4 dense RX sweeps (~256 ops). Exact: embedding RXs act on |0> product state.
__device__ __forceinline__ void embed(float sr[DIM], float si[DIM], float4 a) {
    float c0, s0, c1, s1, c2, s2, c3, s3;
    __sincosf(0.5f * a.x, &s0, &c0);   // wire 0 -> bit 3
    __sincosf(0.5f * a.y, &s1, &c1);   // wire 1 -> bit 2
    __sincosf(0.5f * a.z, &s2, &c2);   // wire 2 -> bit 1
    __sincosf(0.5f * a.w, &s3, &c3);   // wire 3 -> bit 0
    float A[4] = {c0 * c1, c0 * s1, s0 * c1, s0 * s1};   // bits (b3,b2)
    float B[4] = {c2 * c3, c2 * s3, s2 * c3, s2 * s3};   // bits (b1,b0)
    #pragma unroll
    for (int idx = 0; idx < DIM; ++idx) {
        const float p = A[idx >> 2] * B[idx & 3];
        const int m = __builtin_popcount(idx) & 3;   // compile-time per idx
        // (-i)^m: m=0 -> +1 ; m=1 -> -i ; m=2 -> -1 ; m=3 -> +i
        sr[idx] = (m == 0) ? p : (m == 2) ? -p : 0.f;
        si[idx] = (m == 1) ? -p : (m == 3) ? p : 0.f;
    }
}

__device__ __forceinline__ void layer(float sr[DIM], float si[DIM], float4 w) {
    float ch, sh;
    __sincosf(0.5f * w.x, &sh, &ch); rx_bit<3>(sr, si, ch, sh);
    __sincosf(0.5f * w.y, &sh, &ch); rx_bit<2>(sr, si, ch, sh);
    __sincosf(0.5f * w.z, &sh, &ch); rx_bit<1>(sr, si, ch, sh);
    __sincosf(0.5f * w.w, &sh, &ch); rx_bit<0>(sr, si, ch, sh);
    cnot_g<3,2>(sr, si);
    cnot_g<2,1>(sr, si);
    cnot_g<1,0>(sr, si);
    cnot_g<0,3>(sr, si);
}

__device__ __forceinline__ float4 measure(const float sr[DIM], const float si[DIM]) {
    float e0 = 0.f, e1 = 0.f, e2 = 0.f, e3 = 0.f;
    #pragma unroll
    for (int i = 0; i < DIM; ++i) {
        float p = fmaf(sr[i], sr[i], si[i] * si[i]);
        e0 += (i & 8) ? -p : p;
        e1 += (i & 4) ? -p : p;
        e2 += (i & 2) ? -p : p;
        e3 += (i & 1) ? -p : p;
    }
    return make_float4(e0, e1, e2, e3);
}

// ---------------- kernel 1: Q,K,V circuits (split over blockIdx.y) ---------

__global__ __launch_bounds__(256) void qkv_kernel(
        const float* __restrict__ x,
        const float* __restrict__ wQp, const float* __restrict__ wKp,
        const float* __restrict__ wVp,
        float4* __restrict__ Q, float4* __restrict__ KV) {
    const int i = blockIdx.x * 256 + threadIdx.x;
    const int which = blockIdx.y;          // 0=Q, 1=K, 2=V
    const float4 xv = ((const float4*)x)[i];
    const float* wp = (which == 0) ? wQp : (which == 1) ? wKp : wVp;
    const float4 w = *(const float4*)wp;

    float sr[DIM], si[DIM];
    embed(sr, si, xv);
    layer(sr, si, w);
    const float4 r = measure(sr, si);

    if (which == 0)      Q[i]          = r;
    else if (which == 1) KV[2 * i]     = r;   // K interleaved with V
    else                 KV[2 * i + 1] = r;
}

// ---------------- kernel 2: attention partials -----------------------------
// Block = 256 threads, grid (128 row-groups of 512 rows, 8 key chunks)
// = 1024 blocks = 4 blocks/CU. K/V chunk staged in LDS transposed by key
// PAIRS: kvs[4p..4p+3] = (K0x,K1x,K0y,K1y),(K0z,K1z,K0w,K1w),
// (V0x,V1x,V0y,V1y),(V0z,V1z,V0w,V1w). Compute is fully packed v2f
// (v_pk_fma_f32, 2 keys/lane-op) with transposed accumulators; reads are
// wave-uniform broadcasts. RPT=2 rows/thread amortizes the LDS reads.

__global__ __launch_bounds__(256, 4) void attn_partial(
        const float4* __restrict__ Q, const float4* __restrict__ KV,
        float* __restrict__ pden, float4* __restrict__ pctx, int n) {
    __shared__ float4 kvs[4 * NPAIR];   // 8 KB

    const int rg = blockIdx.x;          // row-group (512 rows)
    const int c  = blockIdx.y;          // key chunk
    const int b  = rg >> 2;             // 4 row-groups per batch

    // ---- staging: thread p < NPAIR transposes one key pair ----
    const float4* KVc = KV + (size_t)b * (2 * SEQ) + c * (2 * CHUNK);
    if (threadIdx.x < NPAIR) {
        const int p = threadIdx.x;
        const float4 K0 = KVc[4 * p + 0];
        const float4 V0 = KVc[4 * p + 1];
        const float4 K1 = KVc[4 * p + 2];
        const float4 V1 = KVc[4 * p + 3];
        kvs[4 * p + 0] = make_float4(K0.x, K1.x, K0.y, K1.y);
        kvs[4 * p + 1] = make_float4(K0.z, K1.z, K0.w, K1.w);
        kvs[4 * p + 2] = make_float4(V0.x, V1.x, V0.y, V1.y);
        kvs[4 * p + 3] = make_float4(V0.z, V1.z, V0.w, V1.w);
    }
    __syncthreads();

    // fold 0.5 (1/sqrt(E)) * log2(e): loop uses raw exp2
    const float SC = 0.72134752044f;
    const int row0 = rg * (256 * RPT) + threadIdx.x;

    v2f qx[RPT], qy[RPT], qz[RPT], qw[RPT];
    #pragma unroll
    for (int j = 0; j < RPT; ++j) {
        const float4 q = Q[row0 + j * 256];
        qx[j] = (v2f){q.x * SC, q.x * SC};
        qy[j] = (v2f){q.y * SC, q.y * SC};
        qz[j] = (v2f){q.z * SC, q.z * SC};
        qw[j] = (v2f){q.w * SC, q.w * SC};
    }

    v2f den[RPT], ax[RPT], ay[RPT], az[RPT], aw[RPT];
    #pragma unroll
    for (int j = 0; j < RPT; ++j) {
        den[j] = (v2f){0.f, 0.f};
        ax[j] = den[j]; ay[j] = den[j]; az[j] = den[j]; aw[j] = den[j];
    }

    const v4f* kvp = (const v4f*)kvs;
    #pragma unroll 4
    for (int p = 0; p < NPAIR; ++p) {
        const v4f kA = kvp[4 * p + 0];   // (K0x,K1x | K0y,K1y)
        const v4f kB = kvp[4 * p + 1];   // (K0z,K1z | K0w,K1w)
        const v4f vA = kvp[4 * p + 2];   // (V0x,V1x | V0y,V1y)
        const v4f vB = kvp[4 * p + 3];   // (V0z,V1z | V0w,V1w)
        const v2f kx = kA.xy, ky = kA.zw, kz = kB.xy, kw = kB.zw;
        const v2f vx = vA.xy, vy = vA.zw, vz = vB.xy, vw = vB.zw;
        #pragma unroll
        for (int j = 0; j < RPT; ++j) {
            v2f s = __builtin_elementwise_fma(qy[j], ky, qx[j] * kx);
            s     = __builtin_elementwise_fma(qz[j], kz, s);
            s     = __builtin_elementwise_fma(qw[j], kw, s);
            const v2f e = (v2f){fexp2(s.x), fexp2(s.y)};   // 2 keys
            den[j] += e;
            ax[j] = __builtin_elementwise_fma(e, vx, ax[j]);
            ay[j] = __builtin_elementwise_fma(e, vy, ay[j]);
            az[j] = __builtin_elementwise_fma(e, vz, az[j]);
            aw[j] = __builtin_elementwise_fma(e, vw, aw[j]);
        }
    }

    #pragma unroll
    for (int j = 0; j < RPT; ++j) {
        const int row = row0 + j * 256;
        pden[c * n + row] = den[j].x + den[j].y;
        pctx[c * n + row] = make_float4(ax[j].x + ax[j].y, ay[j].x + ay[j].y,
                                        az[j].x + az[j].y, aw[j].x + aw[j].y);
    }
}

// ---------------- kernel 3: combine partials + final circuit ---------------

__global__ __launch_bounds__(256) void combine_kernel(
        const float* __restrict__ pden, const float4* __restrict__ pctx,
        const float* __restrict__ wCp, float4* __restrict__ out, int n) {
    const int row = blockIdx.x * 256 + threadIdx.x;

    float d = 0.f;
    float c0 = 0.f, c1 = 0.f, c2 = 0.f, c3 = 0.f;
    #pragma unroll
    for (int c = 0; c < NCHUNK; ++c) {
        d += pden[c * n + row];
        const float4 p = pctx[c * n + row];
        c0 += p.x; c1 += p.y; c2 += p.z; c3 += p.w;
    }
    const float inv = 1.0f / d;
    const float4 ctx = make_float4(c0 * inv, c1 * inv, c2 * inv, c3 * inv);

    const float4 wC = *(const float4*)wCp;
    float sr[DIM], si[DIM];
    embed(sr, si, ctx);
    layer(sr, si, wC);
    out[row] = measure(sr, si);
}

// ---------------- launch ---------------------------------------------------

extern "C" void kernel_launch(void* const* d_in, const int* in_sizes, int n_in,
                              void* d_out, int out_size, void* d_ws, size_t ws_size,
                              hipStream_t stream) {
    const float* x  = (const float*)d_in[0];
    const float* wQ = (const float*)d_in[1];
    const float* wK = (const float*)d_in[2];
    const float* wV = (const float*)d_in[3];
    const float* wC = (const float*)d_in[4];

    const int n = in_sizes[0] / 4;              // B*S = 65536 rows
    float4* Q    = (float4*)d_ws;               // n float4          = 1 MB
    float4* KV   = Q + n;                       // 2n float4         = 2 MB
    float4* pctx = KV + 2 * n;                  // NCHUNK*n float4   = 8 MB
    float*  pden = (float*)(pctx + NCHUNK * n); // NCHUNK*n float    = 2 MB

    dim3 qgrid(n / 256, 3);
    qkv_kernel<<<qgrid, 256, 0, stream>>>(x, wQ, wK, wV, Q, KV);

    dim3 agrid(n / (256 * RPT), NCHUNK);        // (128, 8) = 1024 blocks
    attn_partial<<<agrid, 256, 0, stream>>>(Q, KV, pden, pctx, n);

    combine_kernel<<<n / 256, 256, 0, stream>>>(pden, pctx, wC, (float4*)d_out, n);
}